// Round 2
// baseline (2321.159 us; speedup 1.0000x reference)
//
#include <hip/hip_runtime.h>
#include <hip/hip_bf16.h>
#include <math.h>

// ---------------- problem dims ----------------
#define TT   128
#define BB   128
#define TB   (TT*BB)         // 16384
#define CHW  4096
#define HID  512
#define G4   2048            // 4*HID
#define ZD   8
#define AD   7
#define FE   128
#define LOFK 520             // HID + ZD

typedef __attribute__((ext_vector_type(8))) short short8;
typedef __attribute__((ext_vector_type(4))) float f32x4;

__device__ __forceinline__ unsigned short f2b(float f) {
  unsigned int u = __float_as_uint(f);
  unsigned int r = (u + 0x7FFFu + ((u >> 16) & 1u)) >> 16;
  return (unsigned short)r;
}
__device__ __forceinline__ float b2f(unsigned short us) {
  return __uint_as_float(((unsigned int)us) << 16);
}

__device__ __forceinline__ void glds16(const void* g, void* l) {
  __builtin_amdgcn_global_load_lds((const __attribute__((address_space(1))) void*)g,
                                   (__attribute__((address_space(3))) void*)l, 16, 0, 0);
}

// ============================================================================
// Conv as implicit-GEMM MFMA (verified R3). One block per image, 4 waves.
// ============================================================================
__global__ __launch_bounds__(256) void conv_mfma_kernel(
    const float* __restrict__ x,
    const unsigned short* __restrict__ bp1, const unsigned short* __restrict__ bp2,
    const unsigned short* __restrict__ bp3,
    const float* __restrict__ b1, const float* __restrict__ b2, const float* __restrict__ b3,
    unsigned short* __restrict__ out)
{
  __shared__ unsigned short img[2 * 6400];   // two 20*20*16 bf16 buffers
  const int tid = threadIdx.x;
  const int wv = tid >> 6, lane = tid & 63, quad = lane >> 4, l16 = lane & 15;
  const int imgid = blockIdx.x;
  unsigned short* buf0 = img;
  unsigned short* buf1 = img + 6400;

  {
    int4 z = {0, 0, 0, 0};
    for (int i = tid; i < 1600; i += 256) ((int4*)img)[i] = z;
  }
  __syncthreads();
  const float* src = x + (size_t)imgid * CHW;
  for (int i = tid; i < CHW; i += 256) {
    const int ci = i >> 8, rem = i & 255, y = rem >> 4, xx = rem & 15;
    buf0[(((ci >> 3) * 400) + (y + 2) * 20 + (xx + 2)) * 8 + (ci & 7)] = f2b(src[i]);
  }
  __syncthreads();

  // ---- stage 1: 5x5, K=416 ----
  {
    short8 bf[13];
#pragma unroll
    for (int s = 0; s < 13; ++s)
      bf[s] = *(const short8*)(bp1 + l16 * 416 + s * 32 + quad * 8);
    f32x4 acc[4];
#pragma unroll
    for (int mt = 0; mt < 4; ++mt)
#pragma unroll
      for (int r = 0; r < 4; ++r) acc[mt][r] = 0.f;
#pragma unroll
    for (int s = 0; s < 13; ++s) {
      int t = 2 * s + (quad >> 1); if (t > 24) t = 24;
      const int ky = t / 5, kx = t - ky * 5;
      const int base = ((quad & 1) * 400 + ky * 20 + l16 + kx) * 8;
#pragma unroll
      for (int mt = 0; mt < 4; ++mt) {
        const int y = wv * 4 + mt;
        short8 a = *(const short8*)&buf0[base + y * 160];
        acc[mt] = __builtin_amdgcn_mfma_f32_16x16x32_bf16(a, bf[s], acc[mt], 0, 0, 0);
      }
    }
    const float bias = b1[l16];
#pragma unroll
    for (int mt = 0; mt < 4; ++mt) {
      const int y = wv * 4 + mt;
#pragma unroll
      for (int r = 0; r < 4; ++r) {
        float v = acc[mt][r] + bias;
        v = v > 0.f ? v : 0.01f * v;
        const int xx = quad * 4 + r;
        buf1[(((l16 >> 3) * 400) + (y + 2) * 20 + (xx + 2)) * 8 + (l16 & 7)] = f2b(v);
      }
    }
  }
  __syncthreads();

  // ---- stage 2: 3x3, K=160 ----
  {
    short8 bf[5];
#pragma unroll
    for (int s = 0; s < 5; ++s)
      bf[s] = *(const short8*)(bp2 + l16 * 160 + s * 32 + quad * 8);
    f32x4 acc[4];
#pragma unroll
    for (int mt = 0; mt < 4; ++mt)
#pragma unroll
      for (int r = 0; r < 4; ++r) acc[mt][r] = 0.f;
#pragma unroll
    for (int s = 0; s < 5; ++s) {
      int t = 2 * s + (quad >> 1); if (t > 8) t = 8;
      const int ky = t / 3, kx = t - ky * 3;
      const int base = ((quad & 1) * 400 + (ky + 1) * 20 + l16 + kx + 1) * 8;
#pragma unroll
      for (int mt = 0; mt < 4; ++mt) {
        const int y = wv * 4 + mt;
        short8 a = *(const short8*)&buf1[base + y * 160];
        acc[mt] = __builtin_amdgcn_mfma_f32_16x16x32_bf16(a, bf[s], acc[mt], 0, 0, 0);
      }
    }
    const float bias = b2[l16];
#pragma unroll
    for (int mt = 0; mt < 4; ++mt) {
      const int y = wv * 4 + mt;
#pragma unroll
      for (int r = 0; r < 4; ++r) {
        float v = acc[mt][r] + bias;
        v = v > 0.f ? v : 0.01f * v;
        const int xx = quad * 4 + r;
        buf0[(((l16 >> 3) * 400) + (y + 2) * 20 + (xx + 2)) * 8 + (l16 & 7)] = f2b(v);
      }
    }
  }
  __syncthreads();

  // ---- stage 3: 3x3 -> global bf16 NCHW ----
  {
    short8 bf[5];
#pragma unroll
    for (int s = 0; s < 5; ++s)
      bf[s] = *(const short8*)(bp3 + l16 * 160 + s * 32 + quad * 8);
    f32x4 acc[4];
#pragma unroll
    for (int mt = 0; mt < 4; ++mt)
#pragma unroll
      for (int r = 0; r < 4; ++r) acc[mt][r] = 0.f;
#pragma unroll
    for (int s = 0; s < 5; ++s) {
      int t = 2 * s + (quad >> 1); if (t > 8) t = 8;
      const int ky = t / 3, kx = t - ky * 3;
      const int base = ((quad & 1) * 400 + (ky + 1) * 20 + l16 + kx + 1) * 8;
#pragma unroll
      for (int mt = 0; mt < 4; ++mt) {
        const int y = wv * 4 + mt;
        short8 a = *(const short8*)&buf0[base + y * 160];
        acc[mt] = __builtin_amdgcn_mfma_f32_16x16x32_bf16(a, bf[s], acc[mt], 0, 0, 0);
      }
    }
    const float bias = b3[l16];
    unsigned short* dst = out + (size_t)imgid * CHW;
#pragma unroll
    for (int mt = 0; mt < 4; ++mt) {
      const int y = wv * 4 + mt;
      ushort4 pk;
      float v;
      v = acc[mt][0] + bias; v = v > 0.f ? v : 0.01f * v; pk.x = f2b(v);
      v = acc[mt][1] + bias; v = v > 0.f ? v : 0.01f * v; pk.y = f2b(v);
      v = acc[mt][2] + bias; v = v > 0.f ? v : 0.01f * v; pk.z = f2b(v);
      v = acc[mt][3] + bias; v = v > 0.f ? v : 0.01f * v; pk.w = f2b(v);
      *(ushort4*)(dst + l16 * 256 + y * 16 + quad * 4) = pk;
    }
  }
}

// pack conv weights OIHW fp32 -> Bp[co][k] bf16, k = tap*16+ci, K mult of 32
__global__ void pack_convw(const float* __restrict__ w, unsigned short* __restrict__ bp,
                           int K, int KH) {
  int i = blockIdx.x * 256 + threadIdx.x;
  if (i >= 16 * K) return;
  int co = i / K, k = i - co * K;
  int t = k >> 4, ci = k & 15;
  float v = 0.f;
  if (t < KH * KH) v = w[((co * 16 + ci) * KH + t / KH) * KH + t % KH];
  bp[i] = f2b(v);
}

// ================= bf16 MFMA GEMM: out[N,M] = act(A@W^T + bias) =================
// MODE: 0 = fp32 out, 1 = bf16 out, 2 = gate-packed bf16 out (row*M + (col&511)*4 + (col>>9))
template<bool LEAKY, int MODE>
__global__ __launch_bounds__(256) void mfma_fc(
    const unsigned short* __restrict__ A, const unsigned short* __restrict__ W,
    const float* __restrict__ bias, void* __restrict__ outp, int K, int M) {
  __shared__ unsigned short As[128 * 32];
  __shared__ unsigned short Bs[128 * 32];
  const int tid = threadIdx.x;
  const int wv = tid >> 6, lane = tid & 63;
  const int quad = lane >> 4, l16 = lane & 15;
  const int wr = (wv >> 1) * 64, wc = (wv & 1) * 64;
  const int rb = blockIdx.y * 128, cb = blockIdx.x * 128;

  const int s0 = tid, s1 = tid + 256;
  const int r0 = s0 >> 2, q0 = s0 & 3;
  const int r1 = s1 >> 2, q1 = s1 & 3;
  const unsigned short* A0 = A + (size_t)(rb + r0) * K + q0 * 8;
  const unsigned short* A1 = A + (size_t)(rb + r1) * K + q1 * 8;
  const unsigned short* W0 = W + (size_t)(cb + r0) * K + q0 * 8;
  const unsigned short* W1 = W + (size_t)(cb + r1) * K + q1 * 8;
  void* ldsA0 = (void*)&As[(wv * 64) * 8];
  void* ldsA1 = (void*)&As[(256 + wv * 64) * 8];
  void* ldsB0 = (void*)&Bs[(wv * 64) * 8];
  void* ldsB1 = (void*)&Bs[(256 + wv * 64) * 8];

  f32x4 acc[4][4];
#pragma unroll
  for (int i = 0; i < 4; ++i)
#pragma unroll
    for (int j = 0; j < 4; ++j)
#pragma unroll
      for (int r = 0; r < 4; ++r) acc[i][j][r] = 0.f;

  for (int k0 = 0; k0 < K; k0 += 32) {
    glds16(A0 + k0, ldsA0);
    glds16(A1 + k0, ldsA1);
    glds16(W0 + k0, ldsB0);
    glds16(W1 + k0, ldsB1);
    __syncthreads();
    short8 af[4], bfr[4];
#pragma unroll
    for (int i = 0; i < 4; ++i)
      af[i] = *(const short8*)&As[(wr + i * 16 + l16) * 32 + quad * 8];
#pragma unroll
    for (int j = 0; j < 4; ++j)
      bfr[j] = *(const short8*)&Bs[(wc + j * 16 + l16) * 32 + quad * 8];
#pragma unroll
    for (int i = 0; i < 4; ++i)
#pragma unroll
      for (int j = 0; j < 4; ++j)
        acc[i][j] = __builtin_amdgcn_mfma_f32_16x16x32_bf16(af[i], bfr[j], acc[i][j], 0, 0, 0);
    __syncthreads();
  }

#pragma unroll
  for (int j = 0; j < 4; ++j) {
    const int col = cb + wc + j * 16 + l16;
    const float bj = bias ? bias[col] : 0.f;
#pragma unroll
    for (int i = 0; i < 4; ++i) {
#pragma unroll
      for (int r = 0; r < 4; ++r) {
        const size_t row = rb + wr + i * 16 + quad * 4 + r;
        float v = acc[i][j][r] + bj;
        if (LEAKY) v = v > 0.f ? v : 0.01f * v;
        if (MODE == 0)      ((float*)outp)[row * M + col] = v;
        else if (MODE == 1) ((unsigned short*)outp)[row * M + col] = f2b(v);
        else {
          const size_t idx = row * M + ((size_t)(col & (HID - 1)) * 4 + (col >> 9));
          ((unsigned short*)outp)[idx] = f2b(v);
        }
      }
    }
  }
}

// ============================================================================
// Persistent LSTM v4: 32 blocks x 256 thr. Per step:
//  - single-wave poll of the 32 per-block flags (wave0 lanes<32), then barrier
//  - ALL 64 h u64-loads hoisted & issued back-to-back into registers (deep
//    vmem pipeline: one ~700cy L3 latency instead of 8-16 exposed ones)
//  - then gih(t+1)/done(t+2) prefetch, then compile-time fence, then 16
//    unrolled MFMA chunks consuming hq[] in issue order (counted vmcnt)
//  - register epilogue (c in regs), publish h/feat via LDS-coalesced u64 stores
//  - s_waitcnt vmcnt(0) -> __syncthreads -> tid0 atomic-stores own flag (t+1)
// ============================================================================
__global__ __launch_bounds__(256, 1) void lstm_persistent(
    const unsigned short* __restrict__ gpk,   // bf16 [T][B][HID][4] packed gates_ih
    const unsigned short* __restrict__ whh,   // bf16 [2048][512]
    unsigned short* h0m, unsigned short* h1m, // ping/pong pre-masked h (bf16)
    const float* __restrict__ cm0,            // fp32 [128][512] pre-masked c0
    const int* __restrict__ done,             // [T][128]
    unsigned short* __restrict__ feat,        // bf16 [T][128][512] unmasked h
    unsigned int* flags)                      // [32] monotonic, stride 64 ints
{
  __shared__ unsigned short whs[64][520];
  __shared__ unsigned short hpub[128][16];
  __shared__ unsigned short fpub[128][16];
  const int tid = threadIdx.x, wv = tid >> 6, lane = tid & 63;
  const int quad = lane >> 4, l16 = lane & 15;
  const int bid = blockIdx.x;
  const int j0 = bid * 16;
  const int j = j0 + l16;

  // preload w_hh slice: row rr -> gate g=rr>>4, col j0+(rr&15)
  for (int rr = wv; rr < 64; rr += 4)
    *(short8*)&whs[rr][lane * 8] =
        *(const short8*)(whh + ((size_t)((rr >> 4) * HID + j0 + (rr & 15))) * HID + lane * 8);

  // per-thread cells (i in 2, r in 4): b = wv*32 + i*16 + quad*4 + r, col j
  float creg[2][4], dcur[2][4];
  unsigned long long gcur[2][4], gnxt[2][4];
  int dnxt[2][4];
#pragma unroll
  for (int i = 0; i < 2; ++i)
#pragma unroll
    for (int r = 0; r < 4; ++r) {
      const int b = wv * 32 + i * 16 + quad * 4 + r;
      creg[i][r] = cm0[(size_t)b * HID + j];
      gcur[i][r] = *(const unsigned long long*)(gpk + ((size_t)b * HID + j) * 4);
      dcur[i][r] = 1.f - (float)done[BB + b];
    }
  __syncthreads();

  // invariant per-thread row bases into the h ping/pong buffers
  const size_t hrow0 = (size_t)(wv * 32 + l16) * HID;
  const size_t hrow1 = (size_t)(wv * 32 + 16 + l16) * HID;

  for (int t = 0; t < TT; ++t) {
    const unsigned short* hc = (t & 1) ? h1m : h0m;
    unsigned short* hn = (t & 1) ? h0m : h1m;

    // ---- wait for all 32 producers of h(t): ONE wave polls, rest barrier ----
    if (t > 0) {
      if (wv == 0) {
        const unsigned int need = (unsigned int)t;
        for (;;) {
          unsigned int v = 0xffffffffu;
          if (lane < 32)
            v = __hip_atomic_load(&flags[lane << 6], __ATOMIC_RELAXED, __HIP_MEMORY_SCOPE_AGENT);
          unsigned long long ok = __ballot(v >= need);
          if (ok == ~0ull) break;
          __builtin_amdgcn_s_sleep(1);
        }
      }
      __syncthreads();
    }

    // ---- issue ALL h loads for this step back-to-back (deep vmem pipeline) ----
    unsigned long long hq[16][4];
#pragma unroll
    for (int ci = 0; ci < 16; ++ci) {
      const int m = (ci + (bid >> 1) + 1) & 15;
      const int k = m * 32 + quad * 8;
      const unsigned long long* pa0 = (const unsigned long long*)(hc + hrow0 + k);
      const unsigned long long* pa1 = (const unsigned long long*)(hc + hrow1 + k);
      hq[ci][0] = __hip_atomic_load(pa0,     __ATOMIC_RELAXED, __HIP_MEMORY_SCOPE_AGENT);
      hq[ci][1] = __hip_atomic_load(pa0 + 1, __ATOMIC_RELAXED, __HIP_MEMORY_SCOPE_AGENT);
      hq[ci][2] = __hip_atomic_load(pa1,     __ATOMIC_RELAXED, __HIP_MEMORY_SCOPE_AGENT);
      hq[ci][3] = __hip_atomic_load(pa1 + 1, __ATOMIC_RELAXED, __HIP_MEMORY_SCOPE_AGENT);
    }

    // ---- prefetch next step's gih/done (HBM, consumed only at epilogue) ----
    if (t + 1 < TT) {
      const unsigned short* gn = gpk + (size_t)(t + 1) * BB * HID * 4;
      const int tn2 = (t + 2 < TT) ? t + 2 : TT - 1;
#pragma unroll
      for (int i = 0; i < 2; ++i)
#pragma unroll
        for (int r = 0; r < 4; ++r) {
          const int b = wv * 32 + i * 16 + quad * 4 + r;
          gnxt[i][r] = *(const unsigned long long*)(gn + ((size_t)b * HID + j) * 4);
          dnxt[i][r] = done[(size_t)tn2 * BB + b];
        }
    }

    // keep all the above loads issued BEFORE any MFMA (no compiler re-sinking)
    asm volatile("" ::: "memory");

    f32x4 acc[2][4];
#pragma unroll
    for (int i = 0; i < 2; ++i)
#pragma unroll
      for (int g = 0; g < 4; ++g)
#pragma unroll
        for (int r = 0; r < 4; ++r) acc[i][g][r] = 0.f;

    // ---- 16 k-chunks, fully unrolled, consume hq in issue order ----
#pragma unroll
    for (int ci = 0; ci < 16; ++ci) {
      const int m = (ci + (bid >> 1) + 1) & 15;
      const int k = m * 32 + quad * 8;
      union { unsigned long long q[2]; short8 v; } a0, a1;
      a0.q[0] = hq[ci][0];
      a0.q[1] = hq[ci][1];
      a1.q[0] = hq[ci][2];
      a1.q[1] = hq[ci][3];
      short8 b0 = *(const short8*)&whs[l16][k];
      short8 b1 = *(const short8*)&whs[16 + l16][k];
      short8 b2 = *(const short8*)&whs[32 + l16][k];
      short8 b3 = *(const short8*)&whs[48 + l16][k];
      acc[0][0] = __builtin_amdgcn_mfma_f32_16x16x32_bf16(a0.v, b0, acc[0][0], 0, 0, 0);
      acc[0][1] = __builtin_amdgcn_mfma_f32_16x16x32_bf16(a0.v, b1, acc[0][1], 0, 0, 0);
      acc[0][2] = __builtin_amdgcn_mfma_f32_16x16x32_bf16(a0.v, b2, acc[0][2], 0, 0, 0);
      acc[0][3] = __builtin_amdgcn_mfma_f32_16x16x32_bf16(a0.v, b3, acc[0][3], 0, 0, 0);
      acc[1][0] = __builtin_amdgcn_mfma_f32_16x16x32_bf16(a1.v, b0, acc[1][0], 0, 0, 0);
      acc[1][1] = __builtin_amdgcn_mfma_f32_16x16x32_bf16(a1.v, b1, acc[1][1], 0, 0, 0);
      acc[1][2] = __builtin_amdgcn_mfma_f32_16x16x32_bf16(a1.v, b2, acc[1][2], 0, 0, 0);
      acc[1][3] = __builtin_amdgcn_mfma_f32_16x16x32_bf16(a1.v, b3, acc[1][3], 0, 0, 0);
    }

    // ---- cell epilogue (register-only state), write LDS pub buffers ----
#pragma unroll
    for (int i = 0; i < 2; ++i) {
#pragma unroll
      for (int r = 0; r < 4; ++r) {
        const int b = wv * 32 + i * 16 + quad * 4 + r;
        const unsigned long long gq = gcur[i][r];
        const float gi = acc[i][0][r] + b2f((unsigned short)gq);
        const float gf = acc[i][1][r] + b2f((unsigned short)(gq >> 16));
        const float gg = acc[i][2][r] + b2f((unsigned short)(gq >> 32));
        const float go = acc[i][3][r] + b2f((unsigned short)(gq >> 48));
        const float i_s = 1.f / (1.f + __expf(-gi));
        const float f_s = 1.f / (1.f + __expf(-gf));
        const float o_s = 1.f / (1.f + __expf(-go));
        const float g_t = tanhf(gg);
        const float c_new = f_s * creg[i][r] + i_s * g_t;
        const float h_new = o_s * tanhf(c_new);
        const float mn = dcur[i][r];
        creg[i][r] = c_new * mn;
        hpub[b][l16] = f2b(h_new * mn);
        fpub[b][l16] = f2b(h_new);
      }
    }
    __syncthreads();

    // ---- coalesced publish: 2 u64 feat + 2 u64 h per thread ----
    {
      const int q0 = tid, q1 = tid + 256;
      const unsigned long long fv0 = *(const unsigned long long*)&fpub[q0 >> 2][(q0 & 3) * 4];
      const unsigned long long fv1 = *(const unsigned long long*)&fpub[q1 >> 2][(q1 & 3) * 4];
      *(unsigned long long*)(feat + ((size_t)t * BB + (q0 >> 2)) * HID + j0 + (q0 & 3) * 4) = fv0;
      *(unsigned long long*)(feat + ((size_t)t * BB + (q1 >> 2)) * HID + j0 + (q1 & 3) * 4) = fv1;
      if (t < TT - 1) {
        const unsigned long long hv0 = *(const unsigned long long*)&hpub[q0 >> 2][(q0 & 3) * 4];
        const unsigned long long hv1 = *(const unsigned long long*)&hpub[q1 >> 2][(q1 & 3) * 4];
        __hip_atomic_store((unsigned long long*)(hn + (size_t)(q0 >> 2) * HID + j0 + (q0 & 3) * 4),
                           hv0, __ATOMIC_RELAXED, __HIP_MEMORY_SCOPE_AGENT);
        __hip_atomic_store((unsigned long long*)(hn + (size_t)(q1 >> 2) * HID + j0 + (q1 & 3) * 4),
                           hv1, __ATOMIC_RELAXED, __HIP_MEMORY_SCOPE_AGENT);
      }
      asm volatile("s_waitcnt vmcnt(0)" ::: "memory");
    }
    __syncthreads();   // whole block's h published; also protects hpub reuse
    if (t < TT - 1 && tid == 0)
      __hip_atomic_store(&flags[bid << 6], (unsigned int)(t + 1),
                         __ATOMIC_RELAXED, __HIP_MEMORY_SCOPE_AGENT);

#pragma unroll
    for (int i = 0; i < 2; ++i)
#pragma unroll
      for (int r = 0; r < 4; ++r) {
        gcur[i][r] = gnxt[i][r];
        dcur[i][r] = 1.f - (float)dnxt[i][r];
      }
  }
}

// ================= small prep kernels =================
__global__ void f2b_kernel(const float* __restrict__ in, unsigned short* __restrict__ out, int n) {
  int i = blockIdx.x * 256 + threadIdx.x;
  if (i < n) out[i] = f2b(in[i]);
}
__global__ void lofpack_kernel(const float* __restrict__ lw, unsigned short* __restrict__ out) {
  int i = blockIdx.x * 256 + threadIdx.x;  // 65536
  int r = i >> 9, c = i & 511;
  out[i] = f2b(lw[r * LOFK + c]);
}
__global__ void bias_add_kernel(const float* __restrict__ a, const float* __restrict__ b,
                                float* __restrict__ o, int n) {
  int i = blockIdx.x * 256 + threadIdx.x;
  if (i < n) o[i] = a[i] + b[i];
}
__global__ void lstm_init_kernel(const float* __restrict__ h0, const float* __restrict__ c0,
                                 const int* __restrict__ done0,
                                 unsigned short* __restrict__ hm, float* __restrict__ cmp) {
  int i = blockIdx.x * 256 + threadIdx.x;  // 65536
  int b = i >> 9;
  float m = 1.f - (float)done0[b];
  hm[i] = f2b(h0[i] * m);
  cmp[i] = c0[i] * m;
}

// ================= heads =================
__global__ __launch_bounds__(256) void heads_kernel(
    const float* __restrict__ raw, const float* __restrict__ lw, const float* __restrict__ lb,
    const float* __restrict__ aw, const float* __restrict__ ab,
    const float* __restrict__ cw, const float* __restrict__ cbias,
    const int* __restrict__ z, const int* __restrict__ action,
    float* __restrict__ out) {
  const int lane = threadIdx.x & 63;
  const int s = blockIdx.x * 4 + (threadIdx.x >> 6);
  const int zv = z[s];
  float v0 = raw[(size_t)s * FE + lane]      + lw[(size_t)lane * LOFK + HID + zv]        + lb[lane];
  float v1 = raw[(size_t)s * FE + 64 + lane] + lw[(size_t)(64 + lane) * LOFK + HID + zv] + lb[64 + lane];
  v0 = v0 > 0.f ? v0 : 0.01f * v0;
  v1 = v1 > 0.f ? v1 : 0.01f * v1;

  float logits[AD];
#pragma unroll
  for (int jj = 0; jj < AD; ++jj) {
    float p = aw[jj * FE + lane] * v0 + aw[jj * FE + 64 + lane] * v1;
#pragma unroll
    for (int o = 32; o > 0; o >>= 1) p += __shfl_down(p, o, 64);
    logits[jj] = __shfl(p, 0, 64) + ab[jj];
  }
  float val = cw[lane] * v0 + cw[64 + lane] * v1;
#pragma unroll
  for (int o = 32; o > 0; o >>= 1) val += __shfl_down(val, o, 64);
  val = __shfl(val, 0, 64) + cbias[0];

  float mx = logits[0];
#pragma unroll
  for (int jj = 1; jj < AD; ++jj) mx = fmaxf(mx, logits[jj]);
  float ex[AD], S = 0.f;
#pragma unroll
  for (int jj = 0; jj < AD; ++jj) { ex[jj] = __expf(logits[jj] - mx); S += ex[jj]; }
  const float inv = 1.f / S;
  const float lZ = __logf(S) + mx;
  float ent = 0.f;
#pragma unroll
  for (int jj = 0; jj < AD; ++jj) ent += (ex[jj] * inv) * (logits[jj] - lZ);
  ent = -ent;
  const float lp_a = logits[action[s]] - lZ;

  if (lane < 10) {
    float v;
    if (lane == 0)      v = lp_a;
    else if (lane == 1) v = ent;
    else if (lane == 2) v = val;
    else                v = ex[lane - 3] * inv;
    out[(size_t)s * 10 + lane] = v;
  }
}

// ================= launch =================
extern "C" void kernel_launch(void* const* d_in, const int* in_sizes, int n_in,
                              void* d_out, int out_size, void* d_ws, size_t ws_size,
                              hipStream_t stream) {
  const float* x       = (const float*)d_in[0];
  const int*   done    = (const int*)d_in[1];
  const int*   z       = (const int*)d_in[2];
  const int*   action  = (const int*)d_in[3];
  const float* h0      = (const float*)d_in[4];
  const float* c0      = (const float*)d_in[5];
  const float* conv1_w = (const float*)d_in[6];
  const float* conv1_b = (const float*)d_in[7];
  const float* conv2_w = (const float*)d_in[8];
  const float* conv2_b = (const float*)d_in[9];
  const float* conv3_w = (const float*)d_in[10];
  const float* conv3_b = (const float*)d_in[11];
  const float* fc1_w   = (const float*)d_in[12];
  const float* fc1_b   = (const float*)d_in[13];
  const float* fc2_w   = (const float*)d_in[14];
  const float* fc2_b   = (const float*)d_in[15];
  const float* w_ih    = (const float*)d_in[16];
  const float* w_hh    = (const float*)d_in[17];
  const float* b_ih    = (const float*)d_in[18];
  const float* b_hh    = (const float*)d_in[19];
  const float* lofeat_w= (const float*)d_in[20];
  const float* lofeat_b= (const float*)d_in[21];
  const float* actor_w = (const float*)d_in[22];
  const float* actor_b = (const float*)d_in[23];
  const float* critic_w= (const float*)d_in[24];
  const float* critic_b= (const float*)d_in[25];
  float* out = (float*)d_out;

  // -------- workspace layout --------
  char* p = (char*)d_ws;
  unsigned short* conv3out = (unsigned short*)p;                 // bf16 TB*4096
  unsigned short* gatesP   = (unsigned short*)p;                 // overlay: bf16 TB*2048 packed
  p += (size_t)TB * CHW * 2;
  unsigned short* fc1out   = (unsigned short*)p;   p += (size_t)TB * HID * 2;
  unsigned short* fc2out   = (unsigned short*)p;   p += (size_t)TB * HID * 2;
  unsigned short* feat     = (unsigned short*)p;   p += (size_t)TB * HID * 2;
  float*          rawlf    = (float*)p;            p += (size_t)TB * FE * 4;
  unsigned short* fc1w_bf  = (unsigned short*)p;   p += (size_t)HID * CHW * 2;
  unsigned short* fc2w_bf  = (unsigned short*)p;   p += (size_t)HID * HID * 2;
  unsigned short* wih_bf   = (unsigned short*)p;   p += (size_t)G4 * HID * 2;
  unsigned short* whh_bf   = (unsigned short*)p;   p += (size_t)G4 * HID * 2;
  unsigned short* lofw_bf  = (unsigned short*)p;   p += (size_t)FE * HID * 2;
  unsigned short* bp1      = (unsigned short*)p;   p += 16 * 416 * 2;
  unsigned short* bp2      = (unsigned short*)p;   p += 16 * 160 * 2;
  unsigned short* bp3      = (unsigned short*)p;   p += 16 * 160 * 2;
  float*          combbias = (float*)p;            p += (size_t)G4 * 4;
  unsigned short* hmA      = (unsigned short*)p;   p += (size_t)BB * HID * 2;
  unsigned short* hmB      = (unsigned short*)p;   p += (size_t)BB * HID * 2;
  float*          cm       = (float*)p;            p += (size_t)BB * HID * 4;
  unsigned int*   flags    = (unsigned int*)p;     p += 32 * 64 * 4;

  // 0. flags must start at 0 (ws is poisoned 0xAA)
  hipMemsetAsync(flags, 0, 32 * 64 * 4, stream);
  // 1. weight packing / conversions
  pack_convw<<<26, 256, 0, stream>>>(conv1_w, bp1, 416, 5);
  pack_convw<<<10, 256, 0, stream>>>(conv2_w, bp2, 160, 3);
  pack_convw<<<10, 256, 0, stream>>>(conv3_w, bp3, 160, 3);
  f2b_kernel<<<(HID * CHW + 255) / 256, 256, 0, stream>>>(fc1_w, fc1w_bf, HID * CHW);
  f2b_kernel<<<(HID * HID + 255) / 256, 256, 0, stream>>>(fc2_w, fc2w_bf, HID * HID);
  f2b_kernel<<<(G4 * HID + 255) / 256, 256, 0, stream>>>(w_ih, wih_bf, G4 * HID);
  f2b_kernel<<<(G4 * HID + 255) / 256, 256, 0, stream>>>(w_hh, whh_bf, G4 * HID);
  lofpack_kernel<<<(FE * HID + 255) / 256, 256, 0, stream>>>(lofeat_w, lofw_bf);
  bias_add_kernel<<<(G4 + 255) / 256, 256, 0, stream>>>(b_ih, b_hh, combbias, G4);
  lstm_init_kernel<<<(BB * HID + 255) / 256, 256, 0, stream>>>(h0, c0, done, hmA, cm);
  // 2. conv stack (MFMA implicit GEMM), bf16 out
  conv_mfma_kernel<<<TB, 256, 0, stream>>>(x, bp1, bp2, bp3,
                                           conv1_b, conv2_b, conv3_b, conv3out);
  // 3. fc1: [TB,4096] x [512,4096]^T -> bf16
  mfma_fc<true, 1><<<dim3(HID / 128, TB / 128), 256, 0, stream>>>(
      conv3out, fc1w_bf, fc1_b, fc1out, CHW, HID);
  // 4. fc2
  mfma_fc<true, 1><<<dim3(HID / 128, TB / 128), 256, 0, stream>>>(
      fc1out, fc2w_bf, fc2_b, fc2out, HID, HID);
  // 5. gates_ih (+ combined bias) -> packed bf16 [t][b][j][gate], overlays conv3out
  mfma_fc<false, 2><<<dim3(G4 / 128, TB / 128), 256, 0, stream>>>(
      fc2out, wih_bf, combbias, gatesP, HID, G4);
  // 6. LSTM: single persistent kernel, parallel-flag handshake
  lstm_persistent<<<32, 256, 0, stream>>>(gatesP, whh_bf, hmA, hmB, cm, done, feat, flags);
  // 7. lofeat raw GEMM
  mfma_fc<false, 0><<<dim3(FE / 128, TB / 128), 256, 0, stream>>>(
      feat, lofw_bf, nullptr, rawlf, HID, FE);
  // 8. heads
  heads_kernel<<<TB / 4, 256, 0, stream>>>(rawlf, lofeat_w, lofeat_b, actor_w, actor_b,
                                           critic_w, critic_b, z, action, out);
}

// Round 4
// 1633.263 us; speedup vs baseline: 1.4212x; 1.4212x over previous
//
#include <hip/hip_runtime.h>
#include <hip/hip_bf16.h>
#include <math.h>

// ---------------- problem dims ----------------
#define TT   128
#define BB   128
#define TB   (TT*BB)         // 16384
#define CHW  4096
#define HID  512
#define G4   2048            // 4*HID
#define ZD   8
#define AD   7
#define FE   128
#define LOFK 520             // HID + ZD

typedef __attribute__((ext_vector_type(8))) short short8;
typedef __attribute__((ext_vector_type(4))) float f32x4;

__device__ __forceinline__ unsigned short f2b(float f) {
  unsigned int u = __float_as_uint(f);
  unsigned int r = (u + 0x7FFFu + ((u >> 16) & 1u)) >> 16;
  return (unsigned short)r;
}
__device__ __forceinline__ float b2f(unsigned short us) {
  return __uint_as_float(((unsigned int)us) << 16);
}

__device__ __forceinline__ void glds16(const void* g, void* l) {
  __builtin_amdgcn_global_load_lds((const __attribute__((address_space(1))) void*)g,
                                   (__attribute__((address_space(3))) void*)l, 16, 0, 0);
}

// ============================================================================
// Conv as implicit-GEMM MFMA (verified R3). One block per image, 4 waves.
// ============================================================================
__global__ __launch_bounds__(256) void conv_mfma_kernel(
    const float* __restrict__ x,
    const unsigned short* __restrict__ bp1, const unsigned short* __restrict__ bp2,
    const unsigned short* __restrict__ bp3,
    const float* __restrict__ b1, const float* __restrict__ b2, const float* __restrict__ b3,
    unsigned short* __restrict__ out)
{
  __shared__ unsigned short img[2 * 6400];   // two 20*20*16 bf16 buffers
  const int tid = threadIdx.x;
  const int wv = tid >> 6, lane = tid & 63, quad = lane >> 4, l16 = lane & 15;
  const int imgid = blockIdx.x;
  unsigned short* buf0 = img;
  unsigned short* buf1 = img + 6400;

  {
    int4 z = {0, 0, 0, 0};
    for (int i = tid; i < 1600; i += 256) ((int4*)img)[i] = z;
  }
  __syncthreads();
  const float* src = x + (size_t)imgid * CHW;
  for (int i = tid; i < CHW; i += 256) {
    const int ci = i >> 8, rem = i & 255, y = rem >> 4, xx = rem & 15;
    buf0[(((ci >> 3) * 400) + (y + 2) * 20 + (xx + 2)) * 8 + (ci & 7)] = f2b(src[i]);
  }
  __syncthreads();

  // ---- stage 1: 5x5, K=416 ----
  {
    short8 bf[13];
#pragma unroll
    for (int s = 0; s < 13; ++s)
      bf[s] = *(const short8*)(bp1 + l16 * 416 + s * 32 + quad * 8);
    f32x4 acc[4];
#pragma unroll
    for (int mt = 0; mt < 4; ++mt)
#pragma unroll
      for (int r = 0; r < 4; ++r) acc[mt][r] = 0.f;
#pragma unroll
    for (int s = 0; s < 13; ++s) {
      int t = 2 * s + (quad >> 1); if (t > 24) t = 24;
      const int ky = t / 5, kx = t - ky * 5;
      const int base = ((quad & 1) * 400 + ky * 20 + l16 + kx) * 8;
#pragma unroll
      for (int mt = 0; mt < 4; ++mt) {
        const int y = wv * 4 + mt;
        short8 a = *(const short8*)&buf0[base + y * 160];
        acc[mt] = __builtin_amdgcn_mfma_f32_16x16x32_bf16(a, bf[s], acc[mt], 0, 0, 0);
      }
    }
    const float bias = b1[l16];
#pragma unroll
    for (int mt = 0; mt < 4; ++mt) {
      const int y = wv * 4 + mt;
#pragma unroll
      for (int r = 0; r < 4; ++r) {
        float v = acc[mt][r] + bias;
        v = v > 0.f ? v : 0.01f * v;
        const int xx = quad * 4 + r;
        buf1[(((l16 >> 3) * 400) + (y + 2) * 20 + (xx + 2)) * 8 + (l16 & 7)] = f2b(v);
      }
    }
  }
  __syncthreads();

  // ---- stage 2: 3x3, K=160 ----
  {
    short8 bf[5];
#pragma unroll
    for (int s = 0; s < 5; ++s)
      bf[s] = *(const short8*)(bp2 + l16 * 160 + s * 32 + quad * 8);
    f32x4 acc[4];
#pragma unroll
    for (int mt = 0; mt < 4; ++mt)
#pragma unroll
      for (int r = 0; r < 4; ++r) acc[mt][r] = 0.f;
#pragma unroll
    for (int s = 0; s < 5; ++s) {
      int t = 2 * s + (quad >> 1); if (t > 8) t = 8;
      const int ky = t / 3, kx = t - ky * 3;
      const int base = ((quad & 1) * 400 + (ky + 1) * 20 + l16 + kx + 1) * 8;
#pragma unroll
      for (int mt = 0; mt < 4; ++mt) {
        const int y = wv * 4 + mt;
        short8 a = *(const short8*)&buf1[base + y * 160];
        acc[mt] = __builtin_amdgcn_mfma_f32_16x16x32_bf16(a, bf[s], acc[mt], 0, 0, 0);
      }
    }
    const float bias = b2[l16];
#pragma unroll
    for (int mt = 0; mt < 4; ++mt) {
      const int y = wv * 4 + mt;
#pragma unroll
      for (int r = 0; r < 4; ++r) {
        float v = acc[mt][r] + bias;
        v = v > 0.f ? v : 0.01f * v;
        const int xx = quad * 4 + r;
        buf0[(((l16 >> 3) * 400) + (y + 2) * 20 + (xx + 2)) * 8 + (l16 & 7)] = f2b(v);
      }
    }
  }
  __syncthreads();

  // ---- stage 3: 3x3 -> global bf16 NCHW ----
  {
    short8 bf[5];
#pragma unroll
    for (int s = 0; s < 5; ++s)
      bf[s] = *(const short8*)(bp3 + l16 * 160 + s * 32 + quad * 8);
    f32x4 acc[4];
#pragma unroll
    for (int mt = 0; mt < 4; ++mt)
#pragma unroll
      for (int r = 0; r < 4; ++r) acc[mt][r] = 0.f;
#pragma unroll
    for (int s = 0; s < 5; ++s) {
      int t = 2 * s + (quad >> 1); if (t > 8) t = 8;
      const int ky = t / 3, kx = t - ky * 3;
      const int base = ((quad & 1) * 400 + (ky + 1) * 20 + l16 + kx + 1) * 8;
#pragma unroll
      for (int mt = 0; mt < 4; ++mt) {
        const int y = wv * 4 + mt;
        short8 a = *(const short8*)&buf0[base + y * 160];
        acc[mt] = __builtin_amdgcn_mfma_f32_16x16x32_bf16(a, bf[s], acc[mt], 0, 0, 0);
      }
    }
    const float bias = b3[l16];
    unsigned short* dst = out + (size_t)imgid * CHW;
#pragma unroll
    for (int mt = 0; mt < 4; ++mt) {
      const int y = wv * 4 + mt;
      ushort4 pk;
      float v;
      v = acc[mt][0] + bias; v = v > 0.f ? v : 0.01f * v; pk.x = f2b(v);
      v = acc[mt][1] + bias; v = v > 0.f ? v : 0.01f * v; pk.y = f2b(v);
      v = acc[mt][2] + bias; v = v > 0.f ? v : 0.01f * v; pk.z = f2b(v);
      v = acc[mt][3] + bias; v = v > 0.f ? v : 0.01f * v; pk.w = f2b(v);
      *(ushort4*)(dst + l16 * 256 + y * 16 + quad * 4) = pk;
    }
  }
}

// pack conv weights OIHW fp32 -> Bp[co][k] bf16, k = tap*16+ci, K mult of 32
__global__ void pack_convw(const float* __restrict__ w, unsigned short* __restrict__ bp,
                           int K, int KH) {
  int i = blockIdx.x * 256 + threadIdx.x;
  if (i >= 16 * K) return;
  int co = i / K, k = i - co * K;
  int t = k >> 4, ci = k & 15;
  float v = 0.f;
  if (t < KH * KH) v = w[((co * 16 + ci) * KH + t / KH) * KH + t % KH];
  bp[i] = f2b(v);
}

// ================= bf16 MFMA GEMM: out[N,M] = act(A@W^T + bias) =================
// MODE: 0 = fp32 out, 1 = bf16 out, 2 = gate-packed bf16 out
// ALAYOUT: 0 = A row-major [N][K]; 1 = A block-major [N/128][K/16][128][16] (feat_bm)
template<bool LEAKY, int MODE, int ALAYOUT>
__global__ __launch_bounds__(256) void mfma_fc(
    const unsigned short* __restrict__ A, const unsigned short* __restrict__ W,
    const float* __restrict__ bias, void* __restrict__ outp, int K, int M) {
  __shared__ unsigned short As[128 * 32];
  __shared__ unsigned short Bs[128 * 32];
  const int tid = threadIdx.x;
  const int wv = tid >> 6, lane = tid & 63;
  const int quad = lane >> 4, l16 = lane & 15;
  const int wr = (wv >> 1) * 64, wc = (wv & 1) * 64;
  const int rb = blockIdx.y * 128, cb = blockIdx.x * 128;

  const int s0 = tid, s1 = tid + 256;
  const int r0 = s0 >> 2, q0 = s0 & 3;
  const int r1 = s1 >> 2, q1 = s1 & 3;
  const unsigned short* A0;
  const unsigned short* A1;
  if (ALAYOUT == 0) {
    A0 = A + (size_t)(rb + r0) * K + q0 * 8;
    A1 = A + (size_t)(rb + r1) * K + q1 * 8;
  } else {
    // feat_bm: [t][32][128][16]; rows rb..rb+127 share t = rb>>7, env = r
    A0 = A + ((size_t)(rb >> 7) * 32 + (q0 >> 1)) * 2048 + (size_t)r0 * 16 + (q0 & 1) * 8;
    A1 = A + ((size_t)(rb >> 7) * 32 + (q1 >> 1)) * 2048 + (size_t)r1 * 16 + (q1 & 1) * 8;
  }
  const unsigned short* W0 = W + (size_t)(cb + r0) * K + q0 * 8;
  const unsigned short* W1 = W + (size_t)(cb + r1) * K + q1 * 8;
  void* ldsA0 = (void*)&As[(wv * 64) * 8];
  void* ldsA1 = (void*)&As[(256 + wv * 64) * 8];
  void* ldsB0 = (void*)&Bs[(wv * 64) * 8];
  void* ldsB1 = (void*)&Bs[(256 + wv * 64) * 8];

  f32x4 acc[4][4];
#pragma unroll
  for (int i = 0; i < 4; ++i)
#pragma unroll
    for (int j = 0; j < 4; ++j)
#pragma unroll
      for (int r = 0; r < 4; ++r) acc[i][j][r] = 0.f;

  for (int k0 = 0; k0 < K; k0 += 32) {
    const int ka = (ALAYOUT == 0) ? k0 : k0 * 128;  // feat_bm: +32 cols = +4096 elems
    glds16(A0 + ka, ldsA0);
    glds16(A1 + ka, ldsA1);
    glds16(W0 + k0, ldsB0);
    glds16(W1 + k0, ldsB1);
    __syncthreads();
    short8 af[4], bfr[4];
#pragma unroll
    for (int i = 0; i < 4; ++i)
      af[i] = *(const short8*)&As[(wr + i * 16 + l16) * 32 + quad * 8];
#pragma unroll
    for (int j = 0; j < 4; ++j)
      bfr[j] = *(const short8*)&Bs[(wc + j * 16 + l16) * 32 + quad * 8];
#pragma unroll
    for (int i = 0; i < 4; ++i)
#pragma unroll
      for (int j = 0; j < 4; ++j)
        acc[i][j] = __builtin_amdgcn_mfma_f32_16x16x32_bf16(af[i], bfr[j], acc[i][j], 0, 0, 0);
    __syncthreads();
  }

#pragma unroll
  for (int j = 0; j < 4; ++j) {
    const int col = cb + wc + j * 16 + l16;
    const float bj = bias ? bias[col] : 0.f;
#pragma unroll
    for (int i = 0; i < 4; ++i) {
#pragma unroll
      for (int r = 0; r < 4; ++r) {
        const size_t row = rb + wr + i * 16 + quad * 4 + r;
        float v = acc[i][j][r] + bj;
        if (LEAKY) v = v > 0.f ? v : 0.01f * v;
        if (MODE == 0)      ((float*)outp)[row * M + col] = v;
        else if (MODE == 1) ((unsigned short*)outp)[row * M + col] = f2b(v);
        else {
          const size_t idx = row * M + ((size_t)(col & (HID - 1)) * 4 + (col >> 9));
          ((unsigned short*)outp)[idx] = f2b(v);
        }
      }
    }
  }
}

// ============================================================================
// Persistent LSTM v5: block-major h exchange (line-complete 4KB bursts),
// feat stores moved off the pre-flag drain, gih/done prefetch above the poll.
// h layout: [32 blk][128 env][16 col]; feat layout: [t][32 blk][128 env][16 col].
// ============================================================================
__global__ __launch_bounds__(256, 1) void lstm_persistent(
    const unsigned short* __restrict__ gpk,   // bf16 [T][B][HID][4] packed gates_ih
    const unsigned short* __restrict__ whh,   // bf16 [2048][512]
    unsigned short* h0m, unsigned short* h1m, // ping/pong pre-masked h (block-major)
    const float* __restrict__ cm0,            // fp32 [128][512] pre-masked c0
    const int* __restrict__ done,             // [T][128]
    unsigned short* __restrict__ feat,        // bf16 feat_bm [T][32][128][16]
    unsigned int* flags)                      // [32] monotonic, stride 64 ints
{
  __shared__ __align__(16) unsigned short whs[64][520];
  __shared__ __align__(16) unsigned short hpub[128][16];
  __shared__ __align__(16) unsigned short fpub[128][16];
  const int tid = threadIdx.x, wv = tid >> 6, lane = tid & 63;
  const int quad = lane >> 4, l16 = lane & 15;
  const int bid = blockIdx.x;
  const int j0 = bid * 16;
  const int j = j0 + l16;

  // preload w_hh slice: row rr -> gate g=rr>>4, col j0+(rr&15)
  for (int rr = wv; rr < 64; rr += 4)
    *(short8*)&whs[rr][lane * 8] =
        *(const short8*)(whh + ((size_t)((rr >> 4) * HID + j0 + (rr & 15))) * HID + lane * 8);

  // per-thread cells (i in 2, r in 4): b = wv*32 + i*16 + quad*4 + r, col j
  float creg[2][4], dcur[2][4];
  unsigned long long gcur[2][4], gnxt[2][4];
  int dnxt[2][4];
#pragma unroll
  for (int i = 0; i < 2; ++i)
#pragma unroll
    for (int r = 0; r < 4; ++r) {
      const int b = wv * 32 + i * 16 + quad * 4 + r;
      creg[i][r] = cm0[(size_t)b * HID + j];
      gcur[i][r] = *(const unsigned long long*)(gpk + ((size_t)b * HID + j) * 4);
      dcur[i][r] = 1.f - (float)done[BB + b];
    }
  __syncthreads();

  // per-thread invariant offsets into a block-major h region
  const int tin = (wv * 32 + l16) * 16 + (quad & 1) * 8;  // ushort offset
  const int qb  = (quad >> 1) * 2048;                     // second producer block of chunk

  for (int t = 0; t < TT; ++t) {
    const unsigned short* hc = (t & 1) ? h1m : h0m;
    unsigned short* hn = (t & 1) ? h0m : h1m;

    // ---- prefetch next step's gih/done FIRST (hides HBM latency under poll) ----
    if (t + 1 < TT) {
      const unsigned short* gn = gpk + (size_t)(t + 1) * BB * HID * 4;
      const int tn2 = (t + 2 < TT) ? t + 2 : TT - 1;
#pragma unroll
      for (int i = 0; i < 2; ++i)
#pragma unroll
        for (int r = 0; r < 4; ++r) {
          const int b = wv * 32 + i * 16 + quad * 4 + r;
          gnxt[i][r] = *(const unsigned long long*)(gn + ((size_t)b * HID + j) * 4);
          dnxt[i][r] = done[(size_t)tn2 * BB + b];
        }
    }
    asm volatile("" ::: "memory");   // pin prefetch issue before the poll

    // ---- wait for all 32 producers of h(t): ONE wave polls, rest barrier ----
    if (t > 0) {
      if (wv == 0) {
        const unsigned int need = (unsigned int)t;
        for (;;) {
          unsigned int v = 0xffffffffu;
          if (lane < 32)
            v = __hip_atomic_load(&flags[lane << 6], __ATOMIC_RELAXED, __HIP_MEMORY_SCOPE_AGENT);
          unsigned long long ok = __ballot(v >= need);
          if (ok == ~0ull) break;
          __builtin_amdgcn_s_sleep(1);
        }
      }
      __syncthreads();
    }

    // ---- issue ALL h loads for this step back-to-back (deep vmem pipeline) ----
    unsigned long long hq[16][4];
#pragma unroll
    for (int ci = 0; ci < 16; ++ci) {
      const int m = (ci + (bid >> 1) + 1) & 15;
      const unsigned short* base = hc + m * 4096 + qb + tin;
      const unsigned long long* p0 = (const unsigned long long*)base;
      const unsigned long long* p1 = (const unsigned long long*)(base + 256);
      hq[ci][0] = __hip_atomic_load(p0,     __ATOMIC_RELAXED, __HIP_MEMORY_SCOPE_AGENT);
      hq[ci][1] = __hip_atomic_load(p0 + 1, __ATOMIC_RELAXED, __HIP_MEMORY_SCOPE_AGENT);
      hq[ci][2] = __hip_atomic_load(p1,     __ATOMIC_RELAXED, __HIP_MEMORY_SCOPE_AGENT);
      hq[ci][3] = __hip_atomic_load(p1 + 1, __ATOMIC_RELAXED, __HIP_MEMORY_SCOPE_AGENT);
    }
    asm volatile("" ::: "memory");   // keep loads issued before MFMAs

    f32x4 acc[2][4];
#pragma unroll
    for (int i = 0; i < 2; ++i)
#pragma unroll
      for (int g = 0; g < 4; ++g)
#pragma unroll
        for (int r = 0; r < 4; ++r) acc[i][g][r] = 0.f;

    // ---- 16 k-chunks, fully unrolled, consume hq in issue order ----
#pragma unroll
    for (int ci = 0; ci < 16; ++ci) {
      const int m = (ci + (bid >> 1) + 1) & 15;
      const int k = m * 32 + quad * 8;
      union { unsigned long long q[2]; short8 v; } a0, a1;
      a0.q[0] = hq[ci][0];
      a0.q[1] = hq[ci][1];
      a1.q[0] = hq[ci][2];
      a1.q[1] = hq[ci][3];
      short8 b0 = *(const short8*)&whs[l16][k];
      short8 b1 = *(const short8*)&whs[16 + l16][k];
      short8 b2 = *(const short8*)&whs[32 + l16][k];
      short8 b3 = *(const short8*)&whs[48 + l16][k];
      acc[0][0] = __builtin_amdgcn_mfma_f32_16x16x32_bf16(a0.v, b0, acc[0][0], 0, 0, 0);
      acc[0][1] = __builtin_amdgcn_mfma_f32_16x16x32_bf16(a0.v, b1, acc[0][1], 0, 0, 0);
      acc[0][2] = __builtin_amdgcn_mfma_f32_16x16x32_bf16(a0.v, b2, acc[0][2], 0, 0, 0);
      acc[0][3] = __builtin_amdgcn_mfma_f32_16x16x32_bf16(a0.v, b3, acc[0][3], 0, 0, 0);
      acc[1][0] = __builtin_amdgcn_mfma_f32_16x16x32_bf16(a1.v, b0, acc[1][0], 0, 0, 0);
      acc[1][1] = __builtin_amdgcn_mfma_f32_16x16x32_bf16(a1.v, b1, acc[1][1], 0, 0, 0);
      acc[1][2] = __builtin_amdgcn_mfma_f32_16x16x32_bf16(a1.v, b2, acc[1][2], 0, 0, 0);
      acc[1][3] = __builtin_amdgcn_mfma_f32_16x16x32_bf16(a1.v, b3, acc[1][3], 0, 0, 0);
    }

    // ---- cell epilogue (register-only state), write LDS pub buffers ----
#pragma unroll
    for (int i = 0; i < 2; ++i) {
#pragma unroll
      for (int r = 0; r < 4; ++r) {
        const int b = wv * 32 + i * 16 + quad * 4 + r;
        const unsigned long long gq = gcur[i][r];
        const float gi = acc[i][0][r] + b2f((unsigned short)gq);
        const float gf = acc[i][1][r] + b2f((unsigned short)(gq >> 16));
        const float gg = acc[i][2][r] + b2f((unsigned short)(gq >> 32));
        const float go = acc[i][3][r] + b2f((unsigned short)(gq >> 48));
        const float i_s = 1.f / (1.f + __expf(-gi));
        const float f_s = 1.f / (1.f + __expf(-gf));
        const float o_s = 1.f / (1.f + __expf(-go));
        const float g_t = tanhf(gg);
        const float c_new = f_s * creg[i][r] + i_s * g_t;
        const float h_new = o_s * tanhf(c_new);
        const float mn = dcur[i][r];
        creg[i][r] = c_new * mn;
        hpub[b][l16] = f2b(h_new * mn);
        fpub[b][l16] = f2b(h_new);
      }
    }
    __syncthreads();

    // ---- publish: h first (line-complete 4KB burst), drain, flag; feat after ----
    if (t < TT - 1) {
      const unsigned long long* hp = (const unsigned long long*)hpub;
      unsigned long long* d = (unsigned long long*)(hn + bid * 2048 + tid * 8);
      __hip_atomic_store(d,     hp[tid * 2],     __ATOMIC_RELAXED, __HIP_MEMORY_SCOPE_AGENT);
      __hip_atomic_store(d + 1, hp[tid * 2 + 1], __ATOMIC_RELAXED, __HIP_MEMORY_SCOPE_AGENT);
      asm volatile("s_waitcnt vmcnt(0)" ::: "memory");
    }
    __syncthreads();   // whole block's h published; also protects hpub reuse
    if (t < TT - 1 && tid == 0)
      __hip_atomic_store(&flags[bid << 6], (unsigned int)(t + 1),
                         __ATOMIC_RELAXED, __HIP_MEMORY_SCOPE_AGENT);

    // feat: fire-and-forget plain store (drains under next step's poll)
    *(int4*)(feat + ((size_t)t * 32 + bid) * 2048 + tid * 8) = ((const int4*)fpub)[tid];

#pragma unroll
    for (int i = 0; i < 2; ++i)
#pragma unroll
      for (int r = 0; r < 4; ++r) {
        gcur[i][r] = gnxt[i][r];
        dcur[i][r] = 1.f - (float)dnxt[i][r];
      }
  }
}

// ================= small prep kernels =================
__global__ void f2b_kernel(const float* __restrict__ in, unsigned short* __restrict__ out, int n) {
  int i = blockIdx.x * 256 + threadIdx.x;
  if (i < n) out[i] = f2b(in[i]);
}
__global__ void lofpack_kernel(const float* __restrict__ lw, unsigned short* __restrict__ out) {
  int i = blockIdx.x * 256 + threadIdx.x;  // 65536
  int r = i >> 9, c = i & 511;
  out[i] = f2b(lw[r * LOFK + c]);
}
__global__ void bias_add_kernel(const float* __restrict__ a, const float* __restrict__ b,
                                float* __restrict__ o, int n) {
  int i = blockIdx.x * 256 + threadIdx.x;
  if (i < n) o[i] = a[i] + b[i];
}
// h0 -> block-major [32][128][16]; c stays env-major
__global__ void lstm_init_kernel(const float* __restrict__ h0, const float* __restrict__ c0,
                                 const int* __restrict__ done0,
                                 unsigned short* __restrict__ hm, float* __restrict__ cmp) {
  int i = blockIdx.x * 256 + threadIdx.x;  // 65536
  int env = i >> 9, col = i & 511;
  float m = 1.f - (float)done0[env];
  hm[(col >> 4) * 2048 + env * 16 + (col & 15)] = f2b(h0[i] * m);
  cmp[i] = c0[i] * m;
}

// ================= heads =================
__global__ __launch_bounds__(256) void heads_kernel(
    const float* __restrict__ raw, const float* __restrict__ lw, const float* __restrict__ lb,
    const float* __restrict__ aw, const float* __restrict__ ab,
    const float* __restrict__ cw, const float* __restrict__ cbias,
    const int* __restrict__ z, const int* __restrict__ action,
    float* __restrict__ out) {
  const int lane = threadIdx.x & 63;
  const int s = blockIdx.x * 4 + (threadIdx.x >> 6);
  const int zv = z[s];
  float v0 = raw[(size_t)s * FE + lane]      + lw[(size_t)lane * LOFK + HID + zv]        + lb[lane];
  float v1 = raw[(size_t)s * FE + 64 + lane] + lw[(size_t)(64 + lane) * LOFK + HID + zv] + lb[64 + lane];
  v0 = v0 > 0.f ? v0 : 0.01f * v0;
  v1 = v1 > 0.f ? v1 : 0.01f * v1;

  float logits[AD];
#pragma unroll
  for (int jj = 0; jj < AD; ++jj) {
    float p = aw[jj * FE + lane] * v0 + aw[jj * FE + 64 + lane] * v1;
#pragma unroll
    for (int o = 32; o > 0; o >>= 1) p += __shfl_down(p, o, 64);
    logits[jj] = __shfl(p, 0, 64) + ab[jj];
  }
  float val = cw[lane] * v0 + cw[64 + lane] * v1;
#pragma unroll
  for (int o = 32; o > 0; o >>= 1) val += __shfl_down(val, o, 64);
  val = __shfl(val, 0, 64) + cbias[0];

  float mx = logits[0];
#pragma unroll
  for (int jj = 1; jj < AD; ++jj) mx = fmaxf(mx, logits[jj]);
  float ex[AD], S = 0.f;
#pragma unroll
  for (int jj = 0; jj < AD; ++jj) { ex[jj] = __expf(logits[jj] - mx); S += ex[jj]; }
  const float inv = 1.f / S;
  const float lZ = __logf(S) + mx;
  float ent = 0.f;
#pragma unroll
  for (int jj = 0; jj < AD; ++jj) ent += (ex[jj] * inv) * (logits[jj] - lZ);
  ent = -ent;
  const float lp_a = logits[action[s]] - lZ;

  if (lane < 10) {
    float v;
    if (lane == 0)      v = lp_a;
    else if (lane == 1) v = ent;
    else if (lane == 2) v = val;
    else                v = ex[lane - 3] * inv;
    out[(size_t)s * 10 + lane] = v;
  }
}

// ================= launch =================
extern "C" void kernel_launch(void* const* d_in, const int* in_sizes, int n_in,
                              void* d_out, int out_size, void* d_ws, size_t ws_size,
                              hipStream_t stream) {
  const float* x       = (const float*)d_in[0];
  const int*   done    = (const int*)d_in[1];
  const int*   z       = (const int*)d_in[2];
  const int*   action  = (const int*)d_in[3];
  const float* h0      = (const float*)d_in[4];
  const float* c0      = (const float*)d_in[5];
  const float* conv1_w = (const float*)d_in[6];
  const float* conv1_b = (const float*)d_in[7];
  const float* conv2_w = (const float*)d_in[8];
  const float* conv2_b = (const float*)d_in[9];
  const float* conv3_w = (const float*)d_in[10];
  const float* conv3_b = (const float*)d_in[11];
  const float* fc1_w   = (const float*)d_in[12];
  const float* fc1_b   = (const float*)d_in[13];
  const float* fc2_w   = (const float*)d_in[14];
  const float* fc2_b   = (const float*)d_in[15];
  const float* w_ih    = (const float*)d_in[16];
  const float* w_hh    = (const float*)d_in[17];
  const float* b_ih    = (const float*)d_in[18];
  const float* b_hh    = (const float*)d_in[19];
  const float* lofeat_w= (const float*)d_in[20];
  const float* lofeat_b= (const float*)d_in[21];
  const float* actor_w = (const float*)d_in[22];
  const float* actor_b = (const float*)d_in[23];
  const float* critic_w= (const float*)d_in[24];
  const float* critic_b= (const float*)d_in[25];
  float* out = (float*)d_out;

  // -------- workspace layout --------
  char* p = (char*)d_ws;
  unsigned short* conv3out = (unsigned short*)p;                 // bf16 TB*4096
  unsigned short* gatesP   = (unsigned short*)p;                 // overlay: bf16 TB*2048 packed
  p += (size_t)TB * CHW * 2;
  unsigned short* fc1out   = (unsigned short*)p;   p += (size_t)TB * HID * 2;
  unsigned short* fc2out   = (unsigned short*)p;   p += (size_t)TB * HID * 2;
  unsigned short* feat     = (unsigned short*)p;   p += (size_t)TB * HID * 2;   // feat_bm
  float*          rawlf    = (float*)p;            p += (size_t)TB * FE * 4;
  unsigned short* fc1w_bf  = (unsigned short*)p;   p += (size_t)HID * CHW * 2;
  unsigned short* fc2w_bf  = (unsigned short*)p;   p += (size_t)HID * HID * 2;
  unsigned short* wih_bf   = (unsigned short*)p;   p += (size_t)G4 * HID * 2;
  unsigned short* whh_bf   = (unsigned short*)p;   p += (size_t)G4 * HID * 2;
  unsigned short* lofw_bf  = (unsigned short*)p;   p += (size_t)FE * HID * 2;
  unsigned short* bp1      = (unsigned short*)p;   p += 16 * 416 * 2;
  unsigned short* bp2      = (unsigned short*)p;   p += 16 * 160 * 2;
  unsigned short* bp3      = (unsigned short*)p;   p += 16 * 160 * 2;
  float*          combbias = (float*)p;            p += (size_t)G4 * 4;
  unsigned short* hmA      = (unsigned short*)p;   p += (size_t)BB * HID * 2;   // block-major
  unsigned short* hmB      = (unsigned short*)p;   p += (size_t)BB * HID * 2;   // block-major
  float*          cm       = (float*)p;            p += (size_t)BB * HID * 4;
  unsigned int*   flags    = (unsigned int*)p;     p += 32 * 64 * 4;

  // 0. flags must start at 0 (ws is poisoned 0xAA)
  hipMemsetAsync(flags, 0, 32 * 64 * 4, stream);
  // 1. weight packing / conversions
  pack_convw<<<26, 256, 0, stream>>>(conv1_w, bp1, 416, 5);
  pack_convw<<<10, 256, 0, stream>>>(conv2_w, bp2, 160, 3);
  pack_convw<<<10, 256, 0, stream>>>(conv3_w, bp3, 160, 3);
  f2b_kernel<<<(HID * CHW + 255) / 256, 256, 0, stream>>>(fc1_w, fc1w_bf, HID * CHW);
  f2b_kernel<<<(HID * HID + 255) / 256, 256, 0, stream>>>(fc2_w, fc2w_bf, HID * HID);
  f2b_kernel<<<(G4 * HID + 255) / 256, 256, 0, stream>>>(w_ih, wih_bf, G4 * HID);
  f2b_kernel<<<(G4 * HID + 255) / 256, 256, 0, stream>>>(w_hh, whh_bf, G4 * HID);
  lofpack_kernel<<<(FE * HID + 255) / 256, 256, 0, stream>>>(lofeat_w, lofw_bf);
  bias_add_kernel<<<(G4 + 255) / 256, 256, 0, stream>>>(b_ih, b_hh, combbias, G4);
  lstm_init_kernel<<<(BB * HID + 255) / 256, 256, 0, stream>>>(h0, c0, done, hmA, cm);
  // 2. conv stack (MFMA implicit GEMM), bf16 out
  conv_mfma_kernel<<<TB, 256, 0, stream>>>(x, bp1, bp2, bp3,
                                           conv1_b, conv2_b, conv3_b, conv3out);
  // 3. fc1: [TB,4096] x [512,4096]^T -> bf16
  mfma_fc<true, 1, 0><<<dim3(HID / 128, TB / 128), 256, 0, stream>>>(
      conv3out, fc1w_bf, fc1_b, fc1out, CHW, HID);
  // 4. fc2
  mfma_fc<true, 1, 0><<<dim3(HID / 128, TB / 128), 256, 0, stream>>>(
      fc1out, fc2w_bf, fc2_b, fc2out, HID, HID);
  // 5. gates_ih (+ combined bias) -> packed bf16 [t][b][j][gate], overlays conv3out
  mfma_fc<false, 2, 0><<<dim3(G4 / 128, TB / 128), 256, 0, stream>>>(
      fc2out, wih_bf, combbias, gatesP, HID, G4);
  // 6. LSTM: single persistent kernel, parallel-flag handshake
  lstm_persistent<<<32, 256, 0, stream>>>(gatesP, whh_bf, hmA, hmB, cm, done, feat, flags);
  // 7. lofeat raw GEMM (A = feat_bm)
  mfma_fc<false, 0, 1><<<dim3(FE / 128, TB / 128), 256, 0, stream>>>(
      feat, lofw_bf, nullptr, rawlf, HID, FE);
  // 8. heads
  heads_kernel<<<TB / 4, 256, 0, stream>>>(rawlf, lofeat_w, lofeat_b, actor_w, actor_b,
                                           critic_w, critic_b, z, action, out);
}

// Round 6
// 1380.270 us; speedup vs baseline: 1.6817x; 1.1833x over previous
//
#include <hip/hip_runtime.h>
#include <hip/hip_bf16.h>
#include <math.h>

// ---------------- problem dims ----------------
#define TT   128
#define BB   128
#define TB   (TT*BB)         // 16384
#define CHW  4096
#define HID  512
#define G4   2048            // 4*HID
#define ZD   8
#define AD   7
#define FE   128
#define LOFK 520             // HID + ZD

typedef __attribute__((ext_vector_type(8))) short short8;
typedef __attribute__((ext_vector_type(4))) float f32x4;

__device__ __forceinline__ unsigned short f2b(float f) {
  unsigned int u = __float_as_uint(f);
  unsigned int r = (u + 0x7FFFu + ((u >> 16) & 1u)) >> 16;
  return (unsigned short)r;
}
__device__ __forceinline__ float b2f(unsigned short us) {
  return __uint_as_float(((unsigned int)us) << 16);
}

__device__ __forceinline__ void glds16(const void* g, void* l) {
  __builtin_amdgcn_global_load_lds((const __attribute__((address_space(1))) void*)g,
                                   (__attribute__((address_space(3))) void*)l, 16, 0, 0);
}

// ============================================================================
// Conv as implicit-GEMM MFMA (verified R3). One block per image, 4 waves.
// ============================================================================
__global__ __launch_bounds__(256) void conv_mfma_kernel(
    const float* __restrict__ x,
    const unsigned short* __restrict__ bp1, const unsigned short* __restrict__ bp2,
    const unsigned short* __restrict__ bp3,
    const float* __restrict__ b1, const float* __restrict__ b2, const float* __restrict__ b3,
    unsigned short* __restrict__ out)
{
  __shared__ unsigned short img[2 * 6400];   // two 20*20*16 bf16 buffers
  const int tid = threadIdx.x;
  const int wv = tid >> 6, lane = tid & 63, quad = lane >> 4, l16 = lane & 15;
  const int imgid = blockIdx.x;
  unsigned short* buf0 = img;
  unsigned short* buf1 = img + 6400;

  {
    int4 z = {0, 0, 0, 0};
    for (int i = tid; i < 1600; i += 256) ((int4*)img)[i] = z;
  }
  __syncthreads();
  const float* src = x + (size_t)imgid * CHW;
  for (int i = tid; i < CHW; i += 256) {
    const int ci = i >> 8, rem = i & 255, y = rem >> 4, xx = rem & 15;
    buf0[(((ci >> 3) * 400) + (y + 2) * 20 + (xx + 2)) * 8 + (ci & 7)] = f2b(src[i]);
  }
  __syncthreads();

  // ---- stage 1: 5x5, K=416 ----
  {
    short8 bf[13];
#pragma unroll
    for (int s = 0; s < 13; ++s)
      bf[s] = *(const short8*)(bp1 + l16 * 416 + s * 32 + quad * 8);
    f32x4 acc[4];
#pragma unroll
    for (int mt = 0; mt < 4; ++mt)
#pragma unroll
      for (int r = 0; r < 4; ++r) acc[mt][r] = 0.f;
#pragma unroll
    for (int s = 0; s < 13; ++s) {
      int t = 2 * s + (quad >> 1); if (t > 24) t = 24;
      const int ky = t / 5, kx = t - ky * 5;
      const int base = ((quad & 1) * 400 + ky * 20 + l16 + kx) * 8;
#pragma unroll
      for (int mt = 0; mt < 4; ++mt) {
        const int y = wv * 4 + mt;
        short8 a = *(const short8*)&buf0[base + y * 160];
        acc[mt] = __builtin_amdgcn_mfma_f32_16x16x32_bf16(a, bf[s], acc[mt], 0, 0, 0);
      }
    }
    const float bias = b1[l16];
#pragma unroll
    for (int mt = 0; mt < 4; ++mt) {
      const int y = wv * 4 + mt;
#pragma unroll
      for (int r = 0; r < 4; ++r) {
        float v = acc[mt][r] + bias;
        v = v > 0.f ? v : 0.01f * v;
        const int xx = quad * 4 + r;
        buf1[(((l16 >> 3) * 400) + (y + 2) * 20 + (xx + 2)) * 8 + (l16 & 7)] = f2b(v);
      }
    }
  }
  __syncthreads();

  // ---- stage 2: 3x3, K=160 ----
  {
    short8 bf[5];
#pragma unroll
    for (int s = 0; s < 5; ++s)
      bf[s] = *(const short8*)(bp2 + l16 * 160 + s * 32 + quad * 8);
    f32x4 acc[4];
#pragma unroll
    for (int mt = 0; mt < 4; ++mt)
#pragma unroll
      for (int r = 0; r < 4; ++r) acc[mt][r] = 0.f;
#pragma unroll
    for (int s = 0; s < 5; ++s) {
      int t = 2 * s + (quad >> 1); if (t > 8) t = 8;
      const int ky = t / 3, kx = t - ky * 3;
      const int base = ((quad & 1) * 400 + (ky + 1) * 20 + l16 + kx + 1) * 8;
#pragma unroll
      for (int mt = 0; mt < 4; ++mt) {
        const int y = wv * 4 + mt;
        short8 a = *(const short8*)&buf1[base + y * 160];
        acc[mt] = __builtin_amdgcn_mfma_f32_16x16x32_bf16(a, bf[s], acc[mt], 0, 0, 0);
      }
    }
    const float bias = b2[l16];
#pragma unroll
    for (int mt = 0; mt < 4; ++mt) {
      const int y = wv * 4 + mt;
#pragma unroll
      for (int r = 0; r < 4; ++r) {
        float v = acc[mt][r] + bias;
        v = v > 0.f ? v : 0.01f * v;
        const int xx = quad * 4 + r;
        buf0[(((l16 >> 3) * 400) + (y + 2) * 20 + (xx + 2)) * 8 + (l16 & 7)] = f2b(v);
      }
    }
  }
  __syncthreads();

  // ---- stage 3: 3x3 -> global bf16 NCHW ----
  {
    short8 bf[5];
#pragma unroll
    for (int s = 0; s < 5; ++s)
      bf[s] = *(const short8*)(bp3 + l16 * 160 + s * 32 + quad * 8);
    f32x4 acc[4];
#pragma unroll
    for (int mt = 0; mt < 4; ++mt)
#pragma unroll
      for (int r = 0; r < 4; ++r) acc[mt][r] = 0.f;
#pragma unroll
    for (int s = 0; s < 5; ++s) {
      int t = 2 * s + (quad >> 1); if (t > 8) t = 8;
      const int ky = t / 3, kx = t - ky * 3;
      const int base = ((quad & 1) * 400 + (ky + 1) * 20 + l16 + kx + 1) * 8;
#pragma unroll
      for (int mt = 0; mt < 4; ++mt) {
        const int y = wv * 4 + mt;
        short8 a = *(const short8*)&buf0[base + y * 160];
        acc[mt] = __builtin_amdgcn_mfma_f32_16x16x32_bf16(a, bf[s], acc[mt], 0, 0, 0);
      }
    }
    const float bias = b3[l16];
    unsigned short* dst = out + (size_t)imgid * CHW;
#pragma unroll
    for (int mt = 0; mt < 4; ++mt) {
      const int y = wv * 4 + mt;
      ushort4 pk;
      float v;
      v = acc[mt][0] + bias; v = v > 0.f ? v : 0.01f * v; pk.x = f2b(v);
      v = acc[mt][1] + bias; v = v > 0.f ? v : 0.01f * v; pk.y = f2b(v);
      v = acc[mt][2] + bias; v = v > 0.f ? v : 0.01f * v; pk.z = f2b(v);
      v = acc[mt][3] + bias; v = v > 0.f ? v : 0.01f * v; pk.w = f2b(v);
      *(ushort4*)(dst + l16 * 256 + y * 16 + quad * 4) = pk;
    }
  }
}

// pack conv weights OIHW fp32 -> Bp[co][k] bf16, k = tap*16+ci, K mult of 32
__global__ void pack_convw(const float* __restrict__ w, unsigned short* __restrict__ bp,
                           int K, int KH) {
  int i = blockIdx.x * 256 + threadIdx.x;
  if (i >= 16 * K) return;
  int co = i / K, k = i - co * K;
  int t = k >> 4, ci = k & 15;
  float v = 0.f;
  if (t < KH * KH) v = w[((co * 16 + ci) * KH + t / KH) * KH + t % KH];
  bp[i] = f2b(v);
}

// ================= bf16 MFMA GEMM: out[N,M] = act(A@W^T + bias) =================
// MODE: 0 = fp32 out, 1 = bf16 out, 2 = gate-packed bf16 out
// ALAYOUT: 0 = A row-major [N][K]; 1 = A feat_bm2 [t][8 g][16 s][16 e][32 h]
template<bool LEAKY, int MODE, int ALAYOUT>
__global__ __launch_bounds__(256) void mfma_fc(
    const unsigned short* __restrict__ A, const unsigned short* __restrict__ W,
    const float* __restrict__ bias, void* __restrict__ outp, int K, int M) {
  __shared__ unsigned short As[128 * 32];
  __shared__ unsigned short Bs[128 * 32];
  const int tid = threadIdx.x;
  const int wv = tid >> 6, lane = tid & 63;
  const int quad = lane >> 4, l16 = lane & 15;
  const int wr = (wv >> 1) * 64, wc = (wv & 1) * 64;
  const int rb = blockIdx.y * 128, cb = blockIdx.x * 128;

  const int s0 = tid, s1 = tid + 256;
  const int r0 = s0 >> 2, q0 = s0 & 3;
  const int r1 = s1 >> 2, q1 = s1 & 3;
  const unsigned short* A0;
  const unsigned short* A1;
  if (ALAYOUT == 0) {
    A0 = A + (size_t)(rb + r0) * K + q0 * 8;
    A1 = A + (size_t)(rb + r1) * K + q1 * 8;
  } else {
    // feat_bm2: addr = t*65536 + g*8192 + s*512 + e*32 + h; row r: g=r>>4, e=r&15
    A0 = A + (size_t)(rb >> 7) * 65536 + (r0 >> 4) * 8192 + (r0 & 15) * 32 + q0 * 8;
    A1 = A + (size_t)(rb >> 7) * 65536 + (r1 >> 4) * 8192 + (r1 & 15) * 32 + q1 * 8;
  }
  const unsigned short* W0 = W + (size_t)(cb + r0) * K + q0 * 8;
  const unsigned short* W1 = W + (size_t)(cb + r1) * K + q1 * 8;
  void* ldsA0 = (void*)&As[(wv * 64) * 8];
  void* ldsA1 = (void*)&As[(256 + wv * 64) * 8];
  void* ldsB0 = (void*)&Bs[(wv * 64) * 8];
  void* ldsB1 = (void*)&Bs[(256 + wv * 64) * 8];

  f32x4 acc[4][4];
#pragma unroll
  for (int i = 0; i < 4; ++i)
#pragma unroll
    for (int j = 0; j < 4; ++j)
#pragma unroll
      for (int r = 0; r < 4; ++r) acc[i][j][r] = 0.f;

  for (int k0 = 0; k0 < K; k0 += 32) {
    const int ka = (ALAYOUT == 0) ? k0 : k0 * 16;  // feat_bm2: (k0>>5)*512
    glds16(A0 + ka, ldsA0);
    glds16(A1 + ka, ldsA1);
    glds16(W0 + k0, ldsB0);
    glds16(W1 + k0, ldsB1);
    __syncthreads();
    short8 af[4], bfr[4];
#pragma unroll
    for (int i = 0; i < 4; ++i)
      af[i] = *(const short8*)&As[(wr + i * 16 + l16) * 32 + quad * 8];
#pragma unroll
    for (int j = 0; j < 4; ++j)
      bfr[j] = *(const short8*)&Bs[(wc + j * 16 + l16) * 32 + quad * 8];
#pragma unroll
    for (int i = 0; i < 4; ++i)
#pragma unroll
      for (int j = 0; j < 4; ++j)
        acc[i][j] = __builtin_amdgcn_mfma_f32_16x16x32_bf16(af[i], bfr[j], acc[i][j], 0, 0, 0);
    __syncthreads();
  }

#pragma unroll
  for (int j = 0; j < 4; ++j) {
    const int col = cb + wc + j * 16 + l16;
    const float bj = bias ? bias[col] : 0.f;
#pragma unroll
    for (int i = 0; i < 4; ++i) {
#pragma unroll
      for (int r = 0; r < 4; ++r) {
        const size_t row = rb + wr + i * 16 + quad * 4 + r;
        float v = acc[i][j][r] + bj;
        if (LEAKY) v = v > 0.f ? v : 0.01f * v;
        if (MODE == 0)      ((float*)outp)[row * M + col] = v;
        else if (MODE == 1) ((unsigned short*)outp)[row * M + col] = f2b(v);
        else {
          const size_t idx = row * M + ((size_t)(col & (HID - 1)) * 4 + (col >> 9));
          ((unsigned short*)outp)[idx] = f2b(v);
        }
      }
    }
  }
}

// ============================================================================
// Persistent LSTM v6: env-group x hidden-slice partitioning, 128 blocks.
// LSTM recurrence is per-env independent -> sync only among the 16 blocks of
// an env-group (same XCD under round-robin dispatch; placement is perf-only).
// Block b: g = b&7 owns envs [g*16,g*16+16); s = b>>3 owns hidden
// [s*32,s*32+32) x all 4 gates. W fragments live in 128 VGPRs (loaded once).
// h exchange: hx[8 g][16 s][16 e][32 h] bf16, 1KB line-complete per block.
// Per step: poll 16 flags -> 16 coalesced 16B h-loads -> 32 MFMA/wave ->
// LDS gate regroup (i,f,g,o per hidden) -> cell epilogue -> publish+drain+flag.
// ============================================================================
__global__ __launch_bounds__(256, 1) void lstm_persistent(
    const unsigned short* __restrict__ gpk,   // bf16 [T][B][HID][4] packed gates_ih
    const unsigned short* __restrict__ whh,   // bf16 [2048][512]
    unsigned short* h0m, unsigned short* h1m, // ping/pong hx (pre-masked h)
    const float* __restrict__ cm0,            // fp32 [128][512] pre-masked c0
    const int* __restrict__ done,             // [T][128]
    unsigned short* __restrict__ feat,        // bf16 feat_bm2 [T][8][16][16][32]
    unsigned int* flags)                      // [128] monotonic, stride 64 ints
{
  __shared__ __align__(16) float gl[4 * 528 + 8];        // [gate][16 env][33 pad]
  __shared__ __align__(16) unsigned short hpub[16 * 32];
  __shared__ __align__(16) unsigned short fpub[16 * 32];
  const int tid = threadIdx.x, wv = tid >> 6, lane = tid & 63;
  const int quad = lane >> 4, l16 = lane & 15;
  const int bid = blockIdx.x;
  const int g = bid & 7, s = bid >> 3;
  const int j0 = s * 32;

  // ---- W fragments -> registers. Wave wv = gate wv; cols j0 + jt*16 + l16 ----
  short8 wfrag[2][16];
#pragma unroll
  for (int jt = 0; jt < 2; ++jt)
#pragma unroll
    for (int ci = 0; ci < 16; ++ci)
      wfrag[jt][ci] = *(const short8*)(whh +
          (size_t)(wv * HID + j0 + jt * 16 + l16) * HID + ci * 32 + quad * 8);

  // ---- per-thread cell state: env_t = tid>>4, hids jA, jA+1 ----
  const int env_t = tid >> 4;            // 0..15 (local env)
  const int jA = (tid & 15) * 2;         // 0..30 even (local hidden)
  const int eg = g * 16 + env_t;         // global env
  float creg[2], dcur;
  unsigned long long gcur[2], gnxt[2];
  int dnxt = 0;
  creg[0] = cm0[(size_t)eg * HID + j0 + jA];
  creg[1] = cm0[(size_t)eg * HID + j0 + jA + 1];
  gcur[0] = *(const unsigned long long*)(gpk + ((size_t)eg * HID + j0 + jA) * 4);
  gcur[1] = *(const unsigned long long*)(gpk + ((size_t)eg * HID + j0 + jA + 1) * 4);
  dcur = 1.f - (float)done[BB + eg];
  gnxt[0] = gcur[0]; gnxt[1] = gcur[1];

  for (int t = 0; t < TT; ++t) {
    const unsigned short* hc = (t & 1) ? h1m : h0m;
    unsigned short* hn = (t & 1) ? h0m : h1m;

    // ---- prefetch next step's gih/done (hides HBM latency under poll) ----
    if (t + 1 < TT) {
      const unsigned short* gn = gpk + (size_t)(t + 1) * BB * HID * 4;
      gnxt[0] = *(const unsigned long long*)(gn + ((size_t)eg * HID + j0 + jA) * 4);
      gnxt[1] = *(const unsigned long long*)(gn + ((size_t)eg * HID + j0 + jA + 1) * 4);
      const int tn2 = (t + 2 < TT) ? t + 2 : TT - 1;
      dnxt = done[(size_t)tn2 * BB + eg];
    }
    asm volatile("" ::: "memory");   // pin prefetch issue before the poll

    // ---- wait for the 16 group members' h(t): wave0 polls, rest barrier ----
    if (t > 0) {
      if (wv == 0) {
        const unsigned int need = (unsigned int)t;
        for (;;) {
          unsigned int v = 0xffffffffu;
          if (lane < 16)
            v = __hip_atomic_load(&flags[((lane << 3) | g) << 6],
                                  __ATOMIC_RELAXED, __HIP_MEMORY_SCOPE_AGENT);
          unsigned long long ok = __ballot(v >= need);
          if (ok == ~0ull) break;
          __builtin_amdgcn_s_sleep(1);
        }
      }
      __syncthreads();
    }

    // ---- issue all 16 group-h loads back-to-back (coalesced 16B/lane) ----
    unsigned long long hq[16][2];
#pragma unroll
    for (int ci = 0; ci < 16; ++ci) {
      const unsigned long long* p =
          (const unsigned long long*)(hc + g * 8192 + ci * 512 + l16 * 32 + quad * 8);
      hq[ci][0] = __hip_atomic_load(p,     __ATOMIC_RELAXED, __HIP_MEMORY_SCOPE_AGENT);
      hq[ci][1] = __hip_atomic_load(p + 1, __ATOMIC_RELAXED, __HIP_MEMORY_SCOPE_AGENT);
    }
    asm volatile("" ::: "memory");   // keep loads issued before MFMAs

    f32x4 acc[2];
#pragma unroll
    for (int jt = 0; jt < 2; ++jt)
#pragma unroll
      for (int r = 0; r < 4; ++r) acc[jt][r] = 0.f;

#pragma unroll
    for (int ci = 0; ci < 16; ++ci) {
      union { unsigned long long q[2]; short8 v; } a;
      a.q[0] = hq[ci][0];
      a.q[1] = hq[ci][1];
      acc[0] = __builtin_amdgcn_mfma_f32_16x16x32_bf16(a.v, wfrag[0][ci], acc[0], 0, 0, 0);
      acc[1] = __builtin_amdgcn_mfma_f32_16x16x32_bf16(a.v, wfrag[1][ci], acc[1], 0, 0, 0);
    }

    // ---- regroup raw gates through LDS: gl[gate][env][hid] ----
#pragma unroll
    for (int jt = 0; jt < 2; ++jt)
#pragma unroll
      for (int r = 0; r < 4; ++r)
        gl[wv * 528 + (quad * 4 + r) * 33 + jt * 16 + l16] = acc[jt][r];
    __syncthreads();

    // ---- cell epilogue: 2 hidden units per thread (register state) ----
    {
      unsigned int hw = 0, fw = 0;
#pragma unroll
      for (int pp = 0; pp < 2; ++pp) {
        const int jj = jA + pp;
        const unsigned long long gq = gcur[pp];
        const float gi = gl[0 * 528 + env_t * 33 + jj] + b2f((unsigned short)gq);
        const float gf = gl[1 * 528 + env_t * 33 + jj] + b2f((unsigned short)(gq >> 16));
        const float gg = gl[2 * 528 + env_t * 33 + jj] + b2f((unsigned short)(gq >> 32));
        const float go = gl[3 * 528 + env_t * 33 + jj] + b2f((unsigned short)(gq >> 48));
        const float i_s = 1.f / (1.f + __expf(-gi));
        const float f_s = 1.f / (1.f + __expf(-gf));
        const float o_s = 1.f / (1.f + __expf(-go));
        const float g_t = tanhf(gg);
        const float c_new = f_s * creg[pp] + i_s * g_t;
        const float h_new = o_s * tanhf(c_new);
        creg[pp] = c_new * dcur;
        hw |= (unsigned int)f2b(h_new * dcur) << (16 * pp);
        fw |= (unsigned int)f2b(h_new) << (16 * pp);
      }
      *(unsigned int*)&hpub[env_t * 32 + jA] = hw;
      *(unsigned int*)&fpub[env_t * 32 + jA] = fw;
    }
    __syncthreads();

    // ---- publish own 1KB h slice (wave0), drain, flag; feat after ----
    if (t < TT - 1 && tid < 64) {
      const unsigned long long* hp = (const unsigned long long*)hpub;
      unsigned long long* d = (unsigned long long*)(hn + g * 8192 + s * 512 + tid * 8);
      __hip_atomic_store(d,     hp[tid * 2],     __ATOMIC_RELAXED, __HIP_MEMORY_SCOPE_AGENT);
      __hip_atomic_store(d + 1, hp[tid * 2 + 1], __ATOMIC_RELAXED, __HIP_MEMORY_SCOPE_AGENT);
    }
    asm volatile("s_waitcnt vmcnt(0)" ::: "memory");
    __syncthreads();   // h published; also protects hpub/fpub reuse
    if (t < TT - 1 && tid == 0)
      __hip_atomic_store(&flags[bid << 6], (unsigned int)(t + 1),
                         __ATOMIC_RELAXED, __HIP_MEMORY_SCOPE_AGENT);

    // feat: fire-and-forget (drains under next step's poll)
    if (tid < 64)
      *(int4*)(feat + (size_t)t * 65536 + g * 8192 + s * 512 + tid * 8) =
          ((const int4*)fpub)[tid];

    gcur[0] = gnxt[0];
    gcur[1] = gnxt[1];
    dcur = 1.f - (float)dnxt;
  }
}

// ================= small prep kernels =================
__global__ void f2b_kernel(const float* __restrict__ in, unsigned short* __restrict__ out, int n) {
  int i = blockIdx.x * 256 + threadIdx.x;
  if (i < n) out[i] = f2b(in[i]);
}
__global__ void lofpack_kernel(const float* __restrict__ lw, unsigned short* __restrict__ out) {
  int i = blockIdx.x * 256 + threadIdx.x;  // 65536
  int r = i >> 9, c = i & 511;
  out[i] = f2b(lw[r * LOFK + c]);
}
__global__ void bias_add_kernel(const float* __restrict__ a, const float* __restrict__ b,
                                float* __restrict__ o, int n) {
  int i = blockIdx.x * 256 + threadIdx.x;
  if (i < n) o[i] = a[i] + b[i];
}
// h0 -> hx layout [8 g][16 s][16 e][32 h]; c stays env-major
__global__ void lstm_init_kernel(const float* __restrict__ h0, const float* __restrict__ c0,
                                 const int* __restrict__ done0,
                                 unsigned short* __restrict__ hm, float* __restrict__ cmp) {
  int i = blockIdx.x * 256 + threadIdx.x;  // 65536
  int env = i >> 9, col = i & 511;
  float m = 1.f - (float)done0[env];
  hm[(env >> 4) * 8192 + (col >> 5) * 512 + (env & 15) * 32 + (col & 31)] = f2b(h0[i] * m);
  cmp[i] = c0[i] * m;
}

// ================= heads =================
__global__ __launch_bounds__(256) void heads_kernel(
    const float* __restrict__ raw, const float* __restrict__ lw, const float* __restrict__ lb,
    const float* __restrict__ aw, const float* __restrict__ ab,
    const float* __restrict__ cw, const float* __restrict__ cbias,
    const int* __restrict__ z, const int* __restrict__ action,
    float* __restrict__ out) {
  const int lane = threadIdx.x & 63;
  const int s = blockIdx.x * 4 + (threadIdx.x >> 6);
  const int zv = z[s];
  float v0 = raw[(size_t)s * FE + lane]      + lw[(size_t)lane * LOFK + HID + zv]        + lb[lane];
  float v1 = raw[(size_t)s * FE + 64 + lane] + lw[(size_t)(64 + lane) * LOFK + HID + zv] + lb[64 + lane];
  v0 = v0 > 0.f ? v0 : 0.01f * v0;
  v1 = v1 > 0.f ? v1 : 0.01f * v1;

  float logits[AD];
#pragma unroll
  for (int jj = 0; jj < AD; ++jj) {
    float p = aw[jj * FE + lane] * v0 + aw[jj * FE + 64 + lane] * v1;
#pragma unroll
    for (int o = 32; o > 0; o >>= 1) p += __shfl_down(p, o, 64);
    logits[jj] = __shfl(p, 0, 64) + ab[jj];
  }
  float val = cw[lane] * v0 + cw[64 + lane] * v1;
#pragma unroll
  for (int o = 32; o > 0; o >>= 1) val += __shfl_down(val, o, 64);
  val = __shfl(val, 0, 64) + cbias[0];

  float mx = logits[0];
#pragma unroll
  for (int jj = 1; jj < AD; ++jj) mx = fmaxf(mx, logits[jj]);
  float ex[AD], S = 0.f;
#pragma unroll
  for (int jj = 0; jj < AD; ++jj) { ex[jj] = __expf(logits[jj] - mx); S += ex[jj]; }
  const float inv = 1.f / S;
  const float lZ = __logf(S) + mx;
  float ent = 0.f;
#pragma unroll
  for (int jj = 0; jj < AD; ++jj) ent += (ex[jj] * inv) * (logits[jj] - lZ);
  ent = -ent;
  const float lp_a = logits[action[s]] - lZ;

  if (lane < 10) {
    float v;
    if (lane == 0)      v = lp_a;
    else if (lane == 1) v = ent;
    else if (lane == 2) v = val;
    else                v = ex[lane - 3] * inv;
    out[(size_t)s * 10 + lane] = v;
  }
}

// ================= launch =================
extern "C" void kernel_launch(void* const* d_in, const int* in_sizes, int n_in,
                              void* d_out, int out_size, void* d_ws, size_t ws_size,
                              hipStream_t stream) {
  const float* x       = (const float*)d_in[0];
  const int*   done    = (const int*)d_in[1];
  const int*   z       = (const int*)d_in[2];
  const int*   action  = (const int*)d_in[3];
  const float* h0      = (const float*)d_in[4];
  const float* c0      = (const float*)d_in[5];
  const float* conv1_w = (const float*)d_in[6];
  const float* conv1_b = (const float*)d_in[7];
  const float* conv2_w = (const float*)d_in[8];
  const float* conv2_b = (const float*)d_in[9];
  const float* conv3_w = (const float*)d_in[10];
  const float* conv3_b = (const float*)d_in[11];
  const float* fc1_w   = (const float*)d_in[12];
  const float* fc1_b   = (const float*)d_in[13];
  const float* fc2_w   = (const float*)d_in[14];
  const float* fc2_b   = (const float*)d_in[15];
  const float* w_ih    = (const float*)d_in[16];
  const float* w_hh    = (const float*)d_in[17];
  const float* b_ih    = (const float*)d_in[18];
  const float* b_hh    = (const float*)d_in[19];
  const float* lofeat_w= (const float*)d_in[20];
  const float* lofeat_b= (const float*)d_in[21];
  const float* actor_w = (const float*)d_in[22];
  const float* actor_b = (const float*)d_in[23];
  const float* critic_w= (const float*)d_in[24];
  const float* critic_b= (const float*)d_in[25];
  float* out = (float*)d_out;

  // -------- workspace layout --------
  char* p = (char*)d_ws;
  unsigned short* conv3out = (unsigned short*)p;                 // bf16 TB*4096
  unsigned short* gatesP   = (unsigned short*)p;                 // overlay: bf16 TB*2048 packed
  p += (size_t)TB * CHW * 2;
  unsigned short* fc1out   = (unsigned short*)p;   p += (size_t)TB * HID * 2;
  unsigned short* fc2out   = (unsigned short*)p;   p += (size_t)TB * HID * 2;
  unsigned short* feat     = (unsigned short*)p;   p += (size_t)TB * HID * 2;   // feat_bm2
  float*          rawlf    = (float*)p;            p += (size_t)TB * FE * 4;
  unsigned short* fc1w_bf  = (unsigned short*)p;   p += (size_t)HID * CHW * 2;
  unsigned short* fc2w_bf  = (unsigned short*)p;   p += (size_t)HID * HID * 2;
  unsigned short* wih_bf   = (unsigned short*)p;   p += (size_t)G4 * HID * 2;
  unsigned short* whh_bf   = (unsigned short*)p;   p += (size_t)G4 * HID * 2;
  unsigned short* lofw_bf  = (unsigned short*)p;   p += (size_t)FE * HID * 2;
  unsigned short* bp1      = (unsigned short*)p;   p += 16 * 416 * 2;
  unsigned short* bp2      = (unsigned short*)p;   p += 16 * 160 * 2;
  unsigned short* bp3      = (unsigned short*)p;   p += 16 * 160 * 2;
  float*          combbias = (float*)p;            p += (size_t)G4 * 4;
  unsigned short* hmA      = (unsigned short*)p;   p += (size_t)BB * HID * 2;   // hx ping
  unsigned short* hmB      = (unsigned short*)p;   p += (size_t)BB * HID * 2;   // hx pong
  float*          cm       = (float*)p;            p += (size_t)BB * HID * 4;
  unsigned int*   flags    = (unsigned int*)p;     p += 128 * 64 * 4;

  // 0. flags must start at 0 (ws is poisoned 0xAA)
  hipMemsetAsync(flags, 0, 128 * 64 * 4, stream);
  // 1. weight packing / conversions
  pack_convw<<<26, 256, 0, stream>>>(conv1_w, bp1, 416, 5);
  pack_convw<<<10, 256, 0, stream>>>(conv2_w, bp2, 160, 3);
  pack_convw<<<10, 256, 0, stream>>>(conv3_w, bp3, 160, 3);
  f2b_kernel<<<(HID * CHW + 255) / 256, 256, 0, stream>>>(fc1_w, fc1w_bf, HID * CHW);
  f2b_kernel<<<(HID * HID + 255) / 256, 256, 0, stream>>>(fc2_w, fc2w_bf, HID * HID);
  f2b_kernel<<<(G4 * HID + 255) / 256, 256, 0, stream>>>(w_ih, wih_bf, G4 * HID);
  f2b_kernel<<<(G4 * HID + 255) / 256, 256, 0, stream>>>(w_hh, whh_bf, G4 * HID);
  lofpack_kernel<<<(FE * HID + 255) / 256, 256, 0, stream>>>(lofeat_w, lofw_bf);
  bias_add_kernel<<<(G4 + 255) / 256, 256, 0, stream>>>(b_ih, b_hh, combbias, G4);
  lstm_init_kernel<<<(BB * HID + 255) / 256, 256, 0, stream>>>(h0, c0, done, hmA, cm);
  // 2. conv stack (MFMA implicit GEMM), bf16 out
  conv_mfma_kernel<<<TB, 256, 0, stream>>>(x, bp1, bp2, bp3,
                                           conv1_b, conv2_b, conv3_b, conv3out);
  // 3. fc1: [TB,4096] x [512,4096]^T -> bf16
  mfma_fc<true, 1, 0><<<dim3(HID / 128, TB / 128), 256, 0, stream>>>(
      conv3out, fc1w_bf, fc1_b, fc1out, CHW, HID);
  // 4. fc2
  mfma_fc<true, 1, 0><<<dim3(HID / 128, TB / 128), 256, 0, stream>>>(
      fc1out, fc2w_bf, fc2_b, fc2out, HID, HID);
  // 5. gates_ih (+ combined bias) -> packed bf16 [t][b][j][gate], overlays conv3out
  mfma_fc<false, 2, 0><<<dim3(G4 / 128, TB / 128), 256, 0, stream>>>(
      fc2out, wih_bf, combbias, gatesP, HID, G4);
  // 6. LSTM: 128 persistent blocks, group-local (16-block) handshake
  lstm_persistent<<<128, 256, 0, stream>>>(gatesP, whh_bf, hmA, hmB, cm, done, feat, flags);
  // 7. lofeat raw GEMM (A = feat_bm2)
  mfma_fc<false, 0, 1><<<dim3(FE / 128, TB / 128), 256, 0, stream>>>(
      feat, lofw_bf, nullptr, rawlf, HID, FE);
  // 8. heads
  heads_kernel<<<TB / 4, 256, 0, stream>>>(rawlf, lofeat_w, lofeat_b, actor_w, actor_b,
                                           critic_w, critic_b, z, action, out);
}